// Round 8
// baseline (949.831 us; speedup 1.0000x reference)
//
#include <hip/hip_runtime.h>
#include <stdint.h>

#define BN_EPS 0.001f

typedef float v2f __attribute__((ext_vector_type(2)));

// ---------------------------------------------------------------------------
// Kernel 1: farthest point sampling. One block per batch, 512 thr (8 waves =
// 2 waves/SIMD so LDS/DPP/barrier latency is hidden by a co-resident wave —
// R7 LESSON: at 256 thr (1 wave/SIMD) ~900 cyc/iter of latency was fully
// exposed). 8 pts/thread as 4 x float2. Bit-exact: contract-off distance,
// strict-> argmax chain (R7 LESSON: chain beats eq-scan tree — fewer insts),
// packed (dist_bits<<32)|~idx u64 DPP wave max, readlane publish (R6 LESSON:
// beats exec-masked lane63 store), 8-entry LDS cross-wave reduce redundantly
// by every thread -> ONE barrier/iter. No global stores in the loop.
// ---------------------------------------------------------------------------
__global__ __launch_bounds__(512) void fps_kernel(const float* __restrict__ xyz,
                                                  float* __restrict__ new_xyz) {
#pragma clang fp contract(off)
  __shared__ float px[4096], py[4096], pz[4096];
  __shared__ unsigned long long wk[2][8];   // double-buffered wave winners
  __shared__ int curh[1024];
  const int b = blockIdx.x;
  const int t = threadIdx.x;
  const int lane = t & 63, wid = t >> 6;
  const float* X = xyz + (size_t)b * 4096 * 3;
  v2f x[4], y[4], z[4], dist[4];
#pragma unroll
  for (int j = 0; j < 4; ++j) {
    const int n0 = (2 * j) * 512 + t;
    const int n1 = (2 * j + 1) * 512 + t;
    x[j].x = X[n0 * 3 + 0]; x[j].y = X[n1 * 3 + 0];
    y[j].x = X[n0 * 3 + 1]; y[j].y = X[n1 * 3 + 1];
    z[j].x = X[n0 * 3 + 2]; z[j].y = X[n1 * 3 + 2];
    px[n0] = x[j].x; py[n0] = y[j].x; pz[n0] = z[j].x;
    px[n1] = x[j].y; py[n1] = y[j].y; pz[n1] = z[j].y;
    dist[j] = (v2f){1e10f, 1e10f};
  }
  __syncthreads();
  int cur = 0;
  for (int it = 0; it < 1024; ++it) {
    if (t == 0) curh[it] = cur;         // LDS only: no vmcnt on the barrier
    const float cx = px[cur], cy = py[cur], cz = pz[cur];
    const v2f cxv = {cx, cx}, cyv = {cy, cy}, czv = {cz, cz};
    float bestv = -1.0f;
    int bestj = 0;
#pragma unroll
    for (int j = 0; j < 4; ++j) {
      v2f dx = x[j] - cxv, dy = y[j] - cyv, dz = z[j] - czv;
      v2f d = dx * dx + dy * dy;   // contract off: mul,mul,add — matches ref reduce
      d = d + dz * dz;
      v2f nd = __builtin_elementwise_min(dist[j], d);
      dist[j] = nd;
      if (nd.x > bestv) { bestv = nd.x; bestj = 2 * j; }      // strict >: earliest wins
      if (nd.y > bestv) { bestv = nd.y; bestj = 2 * j + 1; }
    }
    const int besti = bestj * 512 + t;
    // non-negative float: uint order == float order; max(~idx) == min(idx) tie-break
    unsigned long long key =
        ((unsigned long long)__float_as_uint(bestv) << 32) | (unsigned)(~besti);
    // ---- wave64 max-reduce via DPP; result lands in lane 63 ----
#define DPP_STEP(CTRL)                                                                     \
    {                                                                                      \
      unsigned lo_ = (unsigned)key, hi_ = (unsigned)(key >> 32);                           \
      unsigned ls = (unsigned)__builtin_amdgcn_update_dpp((int)lo_, (int)lo_, CTRL, 0xf, 0xf, false); \
      unsigned hs = (unsigned)__builtin_amdgcn_update_dpp((int)hi_, (int)hi_, CTRL, 0xf, 0xf, false); \
      unsigned long long sk = ((unsigned long long)hs << 32) | ls;                         \
      if (sk > key) key = sk;                                                              \
    }
    DPP_STEP(0x111)  // row_shr:1
    DPP_STEP(0x112)  // row_shr:2
    DPP_STEP(0x114)  // row_shr:4
    DPP_STEP(0x118)  // row_shr:8
    DPP_STEP(0x142)  // row_bcast:15
    DPP_STEP(0x143)  // row_bcast:31
#undef DPP_STEP
    const unsigned whi = (unsigned)__builtin_amdgcn_readlane((int)(key >> 32), 63);
    const unsigned wlo = (unsigned)__builtin_amdgcn_readlane((int)key, 63);
    if (lane == 0) wk[it & 1][wid] = ((unsigned long long)whi << 32) | wlo;
    __syncthreads();
    const unsigned long long k0 = wk[it & 1][0], k1 = wk[it & 1][1];
    const unsigned long long k2 = wk[it & 1][2], k3 = wk[it & 1][3];
    const unsigned long long k4 = wk[it & 1][4], k5 = wk[it & 1][5];
    const unsigned long long k6 = wk[it & 1][6], k7 = wk[it & 1][7];
    unsigned long long b01 = (k1 > k0) ? k1 : k0;
    unsigned long long b23 = (k3 > k2) ? k3 : k2;
    unsigned long long b45 = (k5 > k4) ? k5 : k4;
    unsigned long long b67 = (k7 > k6) ? k7 : k6;
    unsigned long long c0 = (b23 > b01) ? b23 : b01;
    unsigned long long c1 = (b67 > b45) ? b67 : b45;
    unsigned long long bk = (c1 > c0) ? c1 : c0;
    cur = (int)(~(unsigned)(bk & 0xffffffffull));
  }
  __syncthreads();
  float* out = new_xyz + (size_t)b * 1024 * 3;
  for (int it = t; it < 1024; it += 512) {
    const int c = curh[it];
    out[it * 3 + 0] = px[c];
    out[it * 3 + 1] = py[c];
    out[it * 3 + 2] = pz[c];
  }
}

// ---------------------------------------------------------------------------
// Kernel 2: ball query. One wave per centroid (4 waves / 256-thr block).
// d2 replicates the reference's lowering exactly:
//   sum(c^2), sum(x^2): separate squares + sequential adds (no FMA) — XLA reduce
//   einsum dot (K=3 gemm): single-accumulator FMA chain k=0,1,2 — gemm microkernel
//   d2 = (csq + sq) - 2*dot, left-assoc, no contraction.   [verified R2-R7: exact]
// ---------------------------------------------------------------------------
__global__ __launch_bounds__(256) void ballq_kernel(const float* __restrict__ xyz,
                                                    const float* __restrict__ new_xyz,
                                                    float* __restrict__ idxf) {
#pragma clang fp contract(off)
  const int wv = threadIdx.x >> 6, lane = threadIdx.x & 63;
  const int pg = blockIdx.x * 4 + wv;  // 0..8191
  const int b = pg >> 10;
  const float* X = xyz + (size_t)b * 4096 * 3;
  const float cx = new_xyz[pg * 3 + 0];
  const float cy = new_xyz[pg * 3 + 1];
  const float cz = new_xyz[pg * 3 + 2];
  const float csq = (cx * cx + cy * cy) + cz * cz;
  float* out = idxf + (size_t)pg * 32;
  int total = 0;
  int first = -1;
  for (int chunk = 0; chunk < 64; ++chunk) {
    const int n = chunk * 64 + lane;
    const float xx = X[n * 3 + 0], yy = X[n * 3 + 1], zz = X[n * 3 + 2];
    const float sq = (xx * xx + yy * yy) + zz * zz;
    const float dot = fmaf(cz, zz, fmaf(cy, yy, cx * xx));  // gemm K-chain
    const float d2 = (csq + sq) - 2.0f * dot;
    const bool in = d2 < 0.04f;
    const unsigned long long mask = __ballot(in);
    if (first < 0 && mask != 0ull) first = chunk * 64 + __builtin_ctzll(mask);
    if (in) {
      const int pos = total + __builtin_popcountll(mask & ((1ull << lane) - 1ull));
      if (pos < 32) out[pos] = (float)n;
    }
    total += __builtin_popcountll(mask);
    if (total >= 32) break;
  }
  if (total < 32 && first >= 0) {
    const int slot = total + lane;
    if (slot < 32) out[slot] = (float)first;
  }
}

// ---------------------------------------------------------------------------
// Kernel 3: gather + 3-layer MLP + maxpool. One 256-thr block handles 4
// centroids sequentially. Activations transposed in LDS; W0+W1 staged in LDS
// once per block; W2 from global (L2-hot). K-loops partially unrolled x4.
// R5 LESSON: full unroll under a tight launch-bounds cap spilled the load
// stream to scratch (4.5 GB HBM/dispatch). R6: this version dropped mlp from
// 1690us to ~200us. Per-accumulator FMA order unchanged -> bit-identical
// output (R2-R7 absmax 0.0).
// ---------------------------------------------------------------------------
__global__ __launch_bounds__(256) void mlp_kernel(
    const float* __restrict__ xyz, const float* __restrict__ points,
    const float* __restrict__ new_xyz, const float* __restrict__ idxf,
    const float* __restrict__ W0, const float* __restrict__ g0,
    const float* __restrict__ b0, const float* __restrict__ m0,
    const float* __restrict__ v0, const float* __restrict__ W1,
    const float* __restrict__ g1, const float* __restrict__ b1,
    const float* __restrict__ m1, const float* __restrict__ v1,
    const float* __restrict__ W2, const float* __restrict__ g2,
    const float* __restrict__ b2, const float* __restrict__ m2,
    const float* __restrict__ v2, float* __restrict__ new_points) {
  __shared__ __align__(16) float W0s[67 * 64];    // 16.75 KB
  __shared__ __align__(16) float W1s[64 * 64];    // 16 KB
  __shared__ __align__(16) float inT[67 * 34];    // [chan][sample], pad 34
  __shared__ __align__(16) float h0T[64 * 34];
  __shared__ __align__(16) float h1T[64 * 36];    // pad 36 -> 16B-aligned float4 rows
  __shared__ float s0c[64], t0c[64], s1c[64], t1c[64], s2c[128], t2c[128];
  const int t = threadIdx.x;

  for (int i = t; i < 67 * 64; i += 256) W0s[i] = W0[i];
  for (int i = t; i < 64 * 64; i += 256) W1s[i] = W1[i];
  if (t < 64) {
    float s = g0[t] * rsqrtf(v0[t] + BN_EPS); s0c[t] = s; t0c[t] = b0[t] - m0[t] * s;
    float u = g1[t] * rsqrtf(v1[t] + BN_EPS); s1c[t] = u; t1c[t] = b1[t] - m1[t] * u;
  }
  if (t < 128) {
    float s = g2[t] * rsqrtf(v2[t] + BN_EPS); s2c[t] = s; t2c[t] = b2[t] - m2[t] * s;
  }
  __syncthreads();

  const int sgrp = t & 15, dgrp = t >> 4;  // L0/L1 tiling: s0=2*sgrp, d0=4*dgrp
  const int dg2 = t & 31, sg2 = t >> 5;    // L2 tiling:    d0=4*dg2,  s0=4*sg2
  float* pmax = h0T;                       // alias (h0T dead by L2 epilogue)

  for (int pp = 0; pp < 4; ++pp) {
    const int pg = blockIdx.x * 4 + pp;
    const int b = pg >> 10;
    const float cx = new_xyz[pg * 3 + 0];
    const float cy = new_xyz[pg * 3 + 1];
    const float cz = new_xyz[pg * 3 + 2];
    // ---- gather stage ----
    {
      const int s = t >> 3, cg = t & 7;
      const int i = (int)idxf[(size_t)pg * 32 + s];
      const float* Pr = points + ((size_t)b * 4096 + i) * 64 + cg * 8;
      const float4 a = *(const float4*)Pr;
      const float4 c4 = *(const float4*)(Pr + 4);
      const int r = 3 + cg * 8;
      inT[(r + 0) * 34 + s] = a.x;  inT[(r + 1) * 34 + s] = a.y;
      inT[(r + 2) * 34 + s] = a.z;  inT[(r + 3) * 34 + s] = a.w;
      inT[(r + 4) * 34 + s] = c4.x; inT[(r + 5) * 34 + s] = c4.y;
      inT[(r + 6) * 34 + s] = c4.z; inT[(r + 7) * 34 + s] = c4.w;
      if (t < 32) {
        const int i2 = (int)idxf[(size_t)pg * 32 + t];
        const float* Xr = xyz + ((size_t)b * 4096 + i2) * 3;
        inT[0 * 34 + t] = Xr[0] - cx;
        inT[1 * 34 + t] = Xr[1] - cy;
        inT[2 * 34 + t] = Xr[2] - cz;
      }
    }
    __syncthreads();
    // ---- L0: 67 -> 64 ----
    {
      float acc[2][4] = {{0, 0, 0, 0}, {0, 0, 0, 0}};
#pragma unroll 4
      for (int c = 0; c < 67; ++c) {
        const float2 a = *(const float2*)&inT[c * 34 + 2 * sgrp];
        const float4 w = *(const float4*)&W0s[c * 64 + 4 * dgrp];
        acc[0][0] = fmaf(a.x, w.x, acc[0][0]); acc[0][1] = fmaf(a.x, w.y, acc[0][1]);
        acc[0][2] = fmaf(a.x, w.z, acc[0][2]); acc[0][3] = fmaf(a.x, w.w, acc[0][3]);
        acc[1][0] = fmaf(a.y, w.x, acc[1][0]); acc[1][1] = fmaf(a.y, w.y, acc[1][1]);
        acc[1][2] = fmaf(a.y, w.z, acc[1][2]); acc[1][3] = fmaf(a.y, w.w, acc[1][3]);
      }
#pragma unroll
      for (int dj = 0; dj < 4; ++dj) {
        const int d = 4 * dgrp + dj;
        const float s = s0c[d], bb = t0c[d];
#pragma unroll
        for (int si = 0; si < 2; ++si) {
          float yv = fmaf(acc[si][dj], s, bb);
          h0T[d * 34 + 2 * sgrp + si] = fmaxf(yv, 0.0f);
        }
      }
    }
    __syncthreads();
    // ---- L1: 64 -> 64 ----
    {
      float acc[2][4] = {{0, 0, 0, 0}, {0, 0, 0, 0}};
#pragma unroll 4
      for (int c = 0; c < 64; ++c) {
        const float2 a = *(const float2*)&h0T[c * 34 + 2 * sgrp];
        const float4 w = *(const float4*)&W1s[c * 64 + 4 * dgrp];
        acc[0][0] = fmaf(a.x, w.x, acc[0][0]); acc[0][1] = fmaf(a.x, w.y, acc[0][1]);
        acc[0][2] = fmaf(a.x, w.z, acc[0][2]); acc[0][3] = fmaf(a.x, w.w, acc[0][3]);
        acc[1][0] = fmaf(a.y, w.x, acc[1][0]); acc[1][1] = fmaf(a.y, w.y, acc[1][1]);
        acc[1][2] = fmaf(a.y, w.z, acc[1][2]); acc[1][3] = fmaf(a.y, w.w, acc[1][3]);
      }
#pragma unroll
      for (int dj = 0; dj < 4; ++dj) {
        const int d = 4 * dgrp + dj;
        const float s = s1c[d], bb = t1c[d];
#pragma unroll
        for (int si = 0; si < 2; ++si) {
          float yv = fmaf(acc[si][dj], s, bb);
          h1T[d * 36 + 2 * sgrp + si] = fmaxf(yv, 0.0f);
        }
      }
    }
    __syncthreads();
    // ---- L2: 64 -> 128, fused BN+ReLU+max over own 4 samples ----
    {
      float acc[4][4] = {{0,0,0,0},{0,0,0,0},{0,0,0,0},{0,0,0,0}};
#pragma unroll 4
      for (int c = 0; c < 64; ++c) {
        const float4 a = *(const float4*)&h1T[c * 36 + 4 * sg2];
        const float4 w = *(const float4*)(W2 + c * 128 + 4 * dg2);
        acc[0][0] = fmaf(a.x, w.x, acc[0][0]); acc[0][1] = fmaf(a.x, w.y, acc[0][1]);
        acc[0][2] = fmaf(a.x, w.z, acc[0][2]); acc[0][3] = fmaf(a.x, w.w, acc[0][3]);
        acc[1][0] = fmaf(a.y, w.x, acc[1][0]); acc[1][1] = fmaf(a.y, w.y, acc[1][1]);
        acc[1][2] = fmaf(a.y, w.z, acc[1][2]); acc[1][3] = fmaf(a.y, w.w, acc[1][3]);
        acc[2][0] = fmaf(a.z, w.x, acc[2][0]); acc[2][1] = fmaf(a.z, w.y, acc[2][1]);
        acc[2][2] = fmaf(a.z, w.z, acc[2][2]); acc[2][3] = fmaf(a.z, w.w, acc[2][3]);
        acc[3][0] = fmaf(a.w, w.x, acc[3][0]); acc[3][1] = fmaf(a.w, w.y, acc[3][1]);
        acc[3][2] = fmaf(a.w, w.z, acc[3][2]); acc[3][3] = fmaf(a.w, w.w, acc[3][3]);
      }
#pragma unroll
      for (int dj = 0; dj < 4; ++dj) {
        const int d = 4 * dg2 + dj;
        const float s = s2c[d], bb = t2c[d];
        float mx = 0.0f;  // relu outputs are >= 0
#pragma unroll
        for (int si = 0; si < 4; ++si) {
          float yv = fmaf(acc[si][dj], s, bb);
          mx = fmaxf(mx, fmaxf(yv, 0.0f));
        }
        pmax[sg2 * 128 + d] = mx;
      }
    }
    __syncthreads();
    if (t < 128) {
      float mx = pmax[t];
#pragma unroll
      for (int g = 1; g < 8; ++g) mx = fmaxf(mx, pmax[g * 128 + t]);
      new_points[(size_t)pg * 128 + t] = mx;
    }
    __syncthreads();
  }
}

extern "C" void kernel_launch(void* const* d_in, const int* in_sizes, int n_in,
                              void* d_out, int out_size, void* d_ws, size_t ws_size,
                              hipStream_t stream) {
  (void)in_sizes; (void)n_in; (void)out_size; (void)d_ws; (void)ws_size;
  const float* xyz    = (const float*)d_in[0];
  const float* points = (const float*)d_in[1];
  const float* W0 = (const float*)d_in[2];
  const float* g0 = (const float*)d_in[3];
  const float* b0 = (const float*)d_in[4];
  const float* m0 = (const float*)d_in[5];
  const float* v0 = (const float*)d_in[6];
  const float* W1 = (const float*)d_in[7];
  const float* g1 = (const float*)d_in[8];
  const float* b1 = (const float*)d_in[9];
  const float* m1 = (const float*)d_in[10];
  const float* v1 = (const float*)d_in[11];
  const float* W2 = (const float*)d_in[12];
  const float* g2 = (const float*)d_in[13];
  const float* b2 = (const float*)d_in[14];
  const float* m2 = (const float*)d_in[15];
  const float* v2 = (const float*)d_in[16];

  float* new_xyz    = (float*)d_out;                 // 8*1024*3
  float* new_points = new_xyz + 8 * 1024 * 3;        // 8*1024*128
  float* idxf       = new_points + 8 * 1024 * 128;   // 8*1024*32 (int values as f32)

  fps_kernel<<<8, 512, 0, stream>>>(xyz, new_xyz);
  ballq_kernel<<<2048, 256, 0, stream>>>(xyz, new_xyz, idxf);
  mlp_kernel<<<2048, 256, 0, stream>>>(xyz, points, new_xyz, idxf,
                                       W0, g0, b0, m0, v0,
                                       W1, g1, b1, m1, v1,
                                       W2, g2, b2, m2, v2, new_points);
}

// Round 9
// 820.423 us; speedup vs baseline: 1.1577x; 1.1577x over previous
//
#include <hip/hip_runtime.h>
#include <stdint.h>

#define BN_EPS 0.001f

typedef float v2f __attribute__((ext_vector_type(2)));

// ---------------------------------------------------------------------------
// Kernel 1: farthest point sampling — BYTE-EXACT REVERT TO R4 (571us, best).
// R6/R7/R8 LESSONS: lane63 exec-masked store (+50us), eq-scan tree argmax
// (+40us), 512-thr (+56us: same-block waves stall on the same barrier; wider
// winner reduce) ALL regressed vs this version. 8 blocks x 256 thr, 16
// pts/thread as 8 x float2. Contract-off distance, strict-> argmax chain,
// packed (dist<<32)|~idx u64 DPP wave max, readlane publish, 4-entry LDS
// cross-wave reduce redundantly by all threads, ONE barrier/iter, no global
// stores in the loop.
// ---------------------------------------------------------------------------
__global__ __launch_bounds__(256) void fps_kernel(const float* __restrict__ xyz,
                                                  float* __restrict__ new_xyz) {
#pragma clang fp contract(off)
  __shared__ float px[4096], py[4096], pz[4096];
  __shared__ unsigned long long wk[2][4];   // double-buffered wave winners
  __shared__ int curh[1024];
  const int b = blockIdx.x;
  const int t = threadIdx.x;
  const int lane = t & 63, wid = t >> 6;
  const float* X = xyz + (size_t)b * 4096 * 3;
  v2f x[8], y[8], z[8], dist[8];
#pragma unroll
  for (int j = 0; j < 8; ++j) {
    const int n0 = (2 * j) * 256 + t;
    const int n1 = (2 * j + 1) * 256 + t;
    x[j].x = X[n0 * 3 + 0]; x[j].y = X[n1 * 3 + 0];
    y[j].x = X[n0 * 3 + 1]; y[j].y = X[n1 * 3 + 1];
    z[j].x = X[n0 * 3 + 2]; z[j].y = X[n1 * 3 + 2];
    px[n0] = x[j].x; py[n0] = y[j].x; pz[n0] = z[j].x;
    px[n1] = x[j].y; py[n1] = y[j].y; pz[n1] = z[j].y;
    dist[j] = (v2f){1e10f, 1e10f};
  }
  __syncthreads();
  int cur = 0;
  for (int it = 0; it < 1024; ++it) {
    if (t == 0) curh[it] = cur;         // LDS only: no vmcnt on the barrier
    const float cx = px[cur], cy = py[cur], cz = pz[cur];
    const v2f cxv = {cx, cx}, cyv = {cy, cy}, czv = {cz, cz};
    float bestv = -1.0f;
    int bestj = 0;
#pragma unroll
    for (int j = 0; j < 8; ++j) {
      v2f dx = x[j] - cxv, dy = y[j] - cyv, dz = z[j] - czv;
      v2f d = dx * dx + dy * dy;   // contract off: mul,mul,add — matches ref reduce
      d = d + dz * dz;
      v2f nd = __builtin_elementwise_min(dist[j], d);
      dist[j] = nd;
      if (nd.x > bestv) { bestv = nd.x; bestj = 2 * j; }      // strict >: earliest wins
      if (nd.y > bestv) { bestv = nd.y; bestj = 2 * j + 1; }
    }
    const int besti = bestj * 256 + t;
    // non-negative float: uint order == float order; max(~idx) == min(idx) tie-break
    unsigned long long key =
        ((unsigned long long)__float_as_uint(bestv) << 32) | (unsigned)(~besti);
    // ---- wave64 max-reduce via DPP; result lands in lane 63 ----
#define DPP_STEP(CTRL)                                                                     \
    {                                                                                      \
      unsigned lo_ = (unsigned)key, hi_ = (unsigned)(key >> 32);                           \
      unsigned ls = (unsigned)__builtin_amdgcn_update_dpp((int)lo_, (int)lo_, CTRL, 0xf, 0xf, false); \
      unsigned hs = (unsigned)__builtin_amdgcn_update_dpp((int)hi_, (int)hi_, CTRL, 0xf, 0xf, false); \
      unsigned long long sk = ((unsigned long long)hs << 32) | ls;                         \
      if (sk > key) key = sk;                                                              \
    }
    DPP_STEP(0x111)  // row_shr:1
    DPP_STEP(0x112)  // row_shr:2
    DPP_STEP(0x114)  // row_shr:4
    DPP_STEP(0x118)  // row_shr:8
    DPP_STEP(0x142)  // row_bcast:15
    DPP_STEP(0x143)  // row_bcast:31
#undef DPP_STEP
    const unsigned whi = (unsigned)__builtin_amdgcn_readlane((int)(key >> 32), 63);
    const unsigned wlo = (unsigned)__builtin_amdgcn_readlane((int)key, 63);
    if (lane == 0) wk[it & 1][wid] = ((unsigned long long)whi << 32) | wlo;
    __syncthreads();
    const unsigned long long k0 = wk[it & 1][0], k1 = wk[it & 1][1];
    const unsigned long long k2 = wk[it & 1][2], k3 = wk[it & 1][3];
    unsigned long long b01 = (k1 > k0) ? k1 : k0;
    unsigned long long b23 = (k3 > k2) ? k3 : k2;
    unsigned long long bk = (b23 > b01) ? b23 : b01;
    cur = (int)(~(unsigned)(bk & 0xffffffffull));
  }
  __syncthreads();
  float* out = new_xyz + (size_t)b * 1024 * 3;
  for (int it = t; it < 1024; it += 256) {
    const int c = curh[it];
    out[it * 3 + 0] = px[c];
    out[it * 3 + 1] = py[c];
    out[it * 3 + 2] = pz[c];
  }
}

// ---------------------------------------------------------------------------
// Kernel 2: ball query. One wave per centroid (4 waves / 256-thr block).
// d2 replicates the reference's lowering exactly:
//   sum(c^2), sum(x^2): separate squares + sequential adds (no FMA) — XLA reduce
//   einsum dot (K=3 gemm): single-accumulator FMA chain k=0,1,2 — gemm microkernel
//   d2 = (csq + sq) - 2*dot, left-assoc, no contraction.   [verified R2-R8: exact]
// ---------------------------------------------------------------------------
__global__ __launch_bounds__(256) void ballq_kernel(const float* __restrict__ xyz,
                                                    const float* __restrict__ new_xyz,
                                                    float* __restrict__ idxf) {
#pragma clang fp contract(off)
  const int wv = threadIdx.x >> 6, lane = threadIdx.x & 63;
  const int pg = blockIdx.x * 4 + wv;  // 0..8191
  const int b = pg >> 10;
  const float* X = xyz + (size_t)b * 4096 * 3;
  const float cx = new_xyz[pg * 3 + 0];
  const float cy = new_xyz[pg * 3 + 1];
  const float cz = new_xyz[pg * 3 + 2];
  const float csq = (cx * cx + cy * cy) + cz * cz;
  float* out = idxf + (size_t)pg * 32;
  int total = 0;
  int first = -1;
  for (int chunk = 0; chunk < 64; ++chunk) {
    const int n = chunk * 64 + lane;
    const float xx = X[n * 3 + 0], yy = X[n * 3 + 1], zz = X[n * 3 + 2];
    const float sq = (xx * xx + yy * yy) + zz * zz;
    const float dot = fmaf(cz, zz, fmaf(cy, yy, cx * xx));  // gemm K-chain
    const float d2 = (csq + sq) - 2.0f * dot;
    const bool in = d2 < 0.04f;
    const unsigned long long mask = __ballot(in);
    if (first < 0 && mask != 0ull) first = chunk * 64 + __builtin_ctzll(mask);
    if (in) {
      const int pos = total + __builtin_popcountll(mask & ((1ull << lane) - 1ull));
      if (pos < 32) out[pos] = (float)n;
    }
    total += __builtin_popcountll(mask);
    if (total >= 32) break;
  }
  if (total < 32 && first >= 0) {
    const int slot = total + lane;
    if (slot < 32) out[slot] = (float)first;
  }
}

// ---------------------------------------------------------------------------
// Kernel 3: gather + 3-layer MLP + maxpool. One 256-thr block handles 4
// centroids sequentially. R9 CHANGES: (1) h1T ALIASES inT (inT dead after L0;
// all reuses barrier-separated) -> LDS 61.4 -> 52.7 KB -> 3 blocks/CU
// (12 waves/CU) for latency overlap; (2) W2 K-loop unroll 8 (8 float4 in
// flight; no launch-bounds cap so no R5-style spill). W0+W1 staged in LDS;
// W2 from global (L2-hot). Per-accumulator FMA order unchanged ->
// bit-identical output (R2-R8 absmax 0.0).
// ---------------------------------------------------------------------------
__global__ __launch_bounds__(256) void mlp_kernel(
    const float* __restrict__ xyz, const float* __restrict__ points,
    const float* __restrict__ new_xyz, const float* __restrict__ idxf,
    const float* __restrict__ W0, const float* __restrict__ g0,
    const float* __restrict__ b0, const float* __restrict__ m0,
    const float* __restrict__ v0, const float* __restrict__ W1,
    const float* __restrict__ g1, const float* __restrict__ b1,
    const float* __restrict__ m1, const float* __restrict__ v1,
    const float* __restrict__ W2, const float* __restrict__ g2,
    const float* __restrict__ b2, const float* __restrict__ m2,
    const float* __restrict__ v2, float* __restrict__ new_points) {
  __shared__ __align__(16) float W0s[67 * 64];    // 16.75 KB
  __shared__ __align__(16) float W1s[64 * 64];    // 16 KB
  __shared__ __align__(16) float sh[64 * 36];     // union: inT (67x34=2278) / h1T (64x36=2304)
  __shared__ __align__(16) float h0T[64 * 34];    // also pmax in epilogue
  __shared__ float s0c[64], t0c[64], s1c[64], t1c[64], s2c[128], t2c[128];
  const int t = threadIdx.x;
  float* inT = sh;   // layout [c][s] stride 34, valid gather..L0
  float* h1T = sh;   // layout [d][s] stride 36, valid L1..L2 (inT dead)

  for (int i = t; i < 67 * 64; i += 256) W0s[i] = W0[i];
  for (int i = t; i < 64 * 64; i += 256) W1s[i] = W1[i];
  if (t < 64) {
    float s = g0[t] * rsqrtf(v0[t] + BN_EPS); s0c[t] = s; t0c[t] = b0[t] - m0[t] * s;
    float u = g1[t] * rsqrtf(v1[t] + BN_EPS); s1c[t] = u; t1c[t] = b1[t] - m1[t] * u;
  }
  if (t < 128) {
    float s = g2[t] * rsqrtf(v2[t] + BN_EPS); s2c[t] = s; t2c[t] = b2[t] - m2[t] * s;
  }
  __syncthreads();

  const int sgrp = t & 15, dgrp = t >> 4;  // L0/L1 tiling: s0=2*sgrp, d0=4*dgrp
  const int dg2 = t & 31, sg2 = t >> 5;    // L2 tiling:    d0=4*dg2,  s0=4*sg2
  float* pmax = h0T;                       // alias (h0T dead by L2 epilogue)

  for (int pp = 0; pp < 4; ++pp) {
    const int pg = blockIdx.x * 4 + pp;
    const int b = pg >> 10;
    const float cx = new_xyz[pg * 3 + 0];
    const float cy = new_xyz[pg * 3 + 1];
    const float cz = new_xyz[pg * 3 + 2];
    // ---- gather stage (writes inT; h1T from previous centroid is dead) ----
    {
      const int s = t >> 3, cg = t & 7;
      const int i = (int)idxf[(size_t)pg * 32 + s];
      const float* Pr = points + ((size_t)b * 4096 + i) * 64 + cg * 8;
      const float4 a = *(const float4*)Pr;
      const float4 c4 = *(const float4*)(Pr + 4);
      const int r = 3 + cg * 8;
      inT[(r + 0) * 34 + s] = a.x;  inT[(r + 1) * 34 + s] = a.y;
      inT[(r + 2) * 34 + s] = a.z;  inT[(r + 3) * 34 + s] = a.w;
      inT[(r + 4) * 34 + s] = c4.x; inT[(r + 5) * 34 + s] = c4.y;
      inT[(r + 6) * 34 + s] = c4.z; inT[(r + 7) * 34 + s] = c4.w;
      if (t < 32) {
        const int i2 = (int)idxf[(size_t)pg * 32 + t];
        const float* Xr = xyz + ((size_t)b * 4096 + i2) * 3;
        inT[0 * 34 + t] = Xr[0] - cx;
        inT[1 * 34 + t] = Xr[1] - cy;
        inT[2 * 34 + t] = Xr[2] - cz;
      }
    }
    __syncthreads();
    // ---- L0: 67 -> 64 (reads inT, writes h0T) ----
    {
      float acc[2][4] = {{0, 0, 0, 0}, {0, 0, 0, 0}};
#pragma unroll 4
      for (int c = 0; c < 67; ++c) {
        const float2 a = *(const float2*)&inT[c * 34 + 2 * sgrp];
        const float4 w = *(const float4*)&W0s[c * 64 + 4 * dgrp];
        acc[0][0] = fmaf(a.x, w.x, acc[0][0]); acc[0][1] = fmaf(a.x, w.y, acc[0][1]);
        acc[0][2] = fmaf(a.x, w.z, acc[0][2]); acc[0][3] = fmaf(a.x, w.w, acc[0][3]);
        acc[1][0] = fmaf(a.y, w.x, acc[1][0]); acc[1][1] = fmaf(a.y, w.y, acc[1][1]);
        acc[1][2] = fmaf(a.y, w.z, acc[1][2]); acc[1][3] = fmaf(a.y, w.w, acc[1][3]);
      }
#pragma unroll
      for (int dj = 0; dj < 4; ++dj) {
        const int d = 4 * dgrp + dj;
        const float s = s0c[d], bb = t0c[d];
#pragma unroll
        for (int si = 0; si < 2; ++si) {
          float yv = fmaf(acc[si][dj], s, bb);
          h0T[d * 34 + 2 * sgrp + si] = fmaxf(yv, 0.0f);
        }
      }
    }
    __syncthreads();
    // ---- L1: 64 -> 64 (reads h0T, writes h1T; inT dead) ----
    {
      float acc[2][4] = {{0, 0, 0, 0}, {0, 0, 0, 0}};
#pragma unroll 4
      for (int c = 0; c < 64; ++c) {
        const float2 a = *(const float2*)&h0T[c * 34 + 2 * sgrp];
        const float4 w = *(const float4*)&W1s[c * 64 + 4 * dgrp];
        acc[0][0] = fmaf(a.x, w.x, acc[0][0]); acc[0][1] = fmaf(a.x, w.y, acc[0][1]);
        acc[0][2] = fmaf(a.x, w.z, acc[0][2]); acc[0][3] = fmaf(a.x, w.w, acc[0][3]);
        acc[1][0] = fmaf(a.y, w.x, acc[1][0]); acc[1][1] = fmaf(a.y, w.y, acc[1][1]);
        acc[1][2] = fmaf(a.y, w.z, acc[1][2]); acc[1][3] = fmaf(a.y, w.w, acc[1][3]);
      }
#pragma unroll
      for (int dj = 0; dj < 4; ++dj) {
        const int d = 4 * dgrp + dj;
        const float s = s1c[d], bb = t1c[d];
#pragma unroll
        for (int si = 0; si < 2; ++si) {
          float yv = fmaf(acc[si][dj], s, bb);
          h1T[d * 36 + 2 * sgrp + si] = fmaxf(yv, 0.0f);
        }
      }
    }
    __syncthreads();
    // ---- L2: 64 -> 128 (reads h1T + global W2), fused BN+ReLU+max ----
    {
      float acc[4][4] = {{0,0,0,0},{0,0,0,0},{0,0,0,0},{0,0,0,0}};
#pragma unroll 8
      for (int c = 0; c < 64; ++c) {
        const float4 a = *(const float4*)&h1T[c * 36 + 4 * sg2];
        const float4 w = *(const float4*)(W2 + c * 128 + 4 * dg2);
        acc[0][0] = fmaf(a.x, w.x, acc[0][0]); acc[0][1] = fmaf(a.x, w.y, acc[0][1]);
        acc[0][2] = fmaf(a.x, w.z, acc[0][2]); acc[0][3] = fmaf(a.x, w.w, acc[0][3]);
        acc[1][0] = fmaf(a.y, w.x, acc[1][0]); acc[1][1] = fmaf(a.y, w.y, acc[1][1]);
        acc[1][2] = fmaf(a.y, w.z, acc[1][2]); acc[1][3] = fmaf(a.y, w.w, acc[1][3]);
        acc[2][0] = fmaf(a.z, w.x, acc[2][0]); acc[2][1] = fmaf(a.z, w.y, acc[2][1]);
        acc[2][2] = fmaf(a.z, w.z, acc[2][2]); acc[2][3] = fmaf(a.z, w.w, acc[2][3]);
        acc[3][0] = fmaf(a.w, w.x, acc[3][0]); acc[3][1] = fmaf(a.w, w.y, acc[3][1]);
        acc[3][2] = fmaf(a.w, w.z, acc[3][2]); acc[3][3] = fmaf(a.w, w.w, acc[3][3]);
      }
#pragma unroll
      for (int dj = 0; dj < 4; ++dj) {
        const int d = 4 * dg2 + dj;
        const float s = s2c[d], bb = t2c[d];
        float mx = 0.0f;  // relu outputs are >= 0
#pragma unroll
        for (int si = 0; si < 4; ++si) {
          float yv = fmaf(acc[si][dj], s, bb);
          mx = fmaxf(mx, fmaxf(yv, 0.0f));
        }
        pmax[sg2 * 128 + d] = mx;
      }
    }
    __syncthreads();
    if (t < 128) {
      float mx = pmax[t];
#pragma unroll
      for (int g = 1; g < 8; ++g) mx = fmaxf(mx, pmax[g * 128 + t]);
      new_points[(size_t)pg * 128 + t] = mx;
    }
    __syncthreads();
  }
}

extern "C" void kernel_launch(void* const* d_in, const int* in_sizes, int n_in,
                              void* d_out, int out_size, void* d_ws, size_t ws_size,
                              hipStream_t stream) {
  (void)in_sizes; (void)n_in; (void)out_size; (void)d_ws; (void)ws_size;
  const float* xyz    = (const float*)d_in[0];
  const float* points = (const float*)d_in[1];
  const float* W0 = (const float*)d_in[2];
  const float* g0 = (const float*)d_in[3];
  const float* b0 = (const float*)d_in[4];
  const float* m0 = (const float*)d_in[5];
  const float* v0 = (const float*)d_in[6];
  const float* W1 = (const float*)d_in[7];
  const float* g1 = (const float*)d_in[8];
  const float* b1 = (const float*)d_in[9];
  const float* m1 = (const float*)d_in[10];
  const float* v1 = (const float*)d_in[11];
  const float* W2 = (const float*)d_in[12];
  const float* g2 = (const float*)d_in[13];
  const float* b2 = (const float*)d_in[14];
  const float* m2 = (const float*)d_in[15];
  const float* v2 = (const float*)d_in[16];

  float* new_xyz    = (float*)d_out;                 // 8*1024*3
  float* new_points = new_xyz + 8 * 1024 * 3;        // 8*1024*128
  float* idxf       = new_points + 8 * 1024 * 128;   // 8*1024*32 (int values as f32)

  fps_kernel<<<8, 256, 0, stream>>>(xyz, new_xyz);
  ballq_kernel<<<2048, 256, 0, stream>>>(xyz, new_xyz, idxf);
  mlp_kernel<<<2048, 256, 0, stream>>>(xyz, points, new_xyz, idxf,
                                       W0, g0, b0, m0, v0,
                                       W1, g1, b1, m1, v1,
                                       W2, g2, b2, m2, v2, new_points);
}